// Round 4
// baseline (499.752 us; speedup 1.0000x reference)
//
#include <hip/hip_runtime.h>
#include <hip/hip_bf16.h>
#include <math.h>
#include <stdint.h>

// GRNN on MI355X — round 4.
// prep_w:        W (k-major) -> Wt bf16 (col-major, k-contiguous) in ws tail.
// gemm_scanprep: tile = 125 rows (one scan chunk) x 64 cols x 3 segments.
//                Epilogue packs (f, u=(1-f)*xt) -> fu dword; r -> out.
// scan_pass1:    per-(col, chunk) local (P = prod f, S = local scan).
// scan_combine:  16-step prefix per col -> c0 table.
// scan_pass2:    c = fma(f,c,u) from c0; h = fma(r, c-x, x) -> out.
// Fallback (ws too small): round-3 kernels (proven).

constexpr int TLEN  = 2000;
constexpr int DDIM  = 512;
constexpr int HH    = 256;
constexpr int N3    = 768;
constexpr int MROWS = 64000;
constexpr int CHUNK = 125;   // 2000 = 16 * 125

// ws layout (bytes)
constexpr size_t FU_OFF = 0;                       // uint32 x 32.768M = 131072000
constexpr size_t WT_OFF = 131072000;               // bf16 x 393216 = 786432
constexpr size_t PS_OFF = WT_OFF + 786432;         // float2 x 16*16384 = 2097152
constexpr size_t C0_OFF = PS_OFF + 2097152;        // float x 16*16384 = 1048576
constexpr size_t WS_NEED = C0_OFF + 1048576;       // 135,004,160

typedef __attribute__((ext_vector_type(8))) short bf16x8;
typedef __attribute__((ext_vector_type(4))) float f32x4;

__device__ __forceinline__ short f2bf(float f) {
    __hip_bfloat16 h = __float2bfloat16(f);
    return *reinterpret_cast<short*>(&h);
}
__device__ __forceinline__ float sigmoidf_(float v) {
    return 1.0f / (1.0f + __expf(-v));
}

// ---------------- prep_w: transpose+convert W -> Wt[half][col][k] ----------------
// 49152 groups of 8 k-elements. grid 192 x 256.
__global__ __launch_bounds__(256) void prep_w(
    const float* __restrict__ W1, const float* __restrict__ W2,
    __hip_bfloat16* __restrict__ Wt)
{
    const int gid  = blockIdx.x * 256 + threadIdx.x;   // 0..49151
    const int j8   = gid & 31;                         // k-group (8 k's)
    const int col  = (gid >> 5) % N3;
    const int half = gid / (32 * N3);
    const float* __restrict__ W = half ? W2 : W1;

    bf16x8 v;
#pragma unroll
    for (int jj = 0; jj < 8; ++jj)
        v[jj] = f2bf(W[(size_t)(j8 * 8 + jj) * N3 + col]);
    *reinterpret_cast<bf16x8*>(Wt + ((size_t)half * N3 + col) * 256 + j8 * 8) = v;
}

// ---------------- gemm_scanprep ----------------
// grid (4 ntiles, 512 chunks, 2 halves), 256 thr (4 waves 2x2 of 64m x 32n).
// K = 256, BK = 64 (4 steps). Block computes xt,f,r (3 segs) for 125x64 cells.
__global__ __launch_bounds__(256) void gemm_scanprep(
    const float* __restrict__ x, const __hip_bfloat16* __restrict__ Wt,
    const float* __restrict__ bf1, const float* __restrict__ br1,
    const float* __restrict__ bf2, const float* __restrict__ br2,
    uint32_t* __restrict__ fu, float* __restrict__ out)
{
    const int nt      = blockIdx.x;   // 64-col tile within half (0..3)
    const int chunkid = blockIdx.y;   // 0..511 (b*16+ch)
    const int half    = blockIdx.z;
    const float* __restrict__ bfb = half ? bf2 : bf1;
    const float* __restrict__ brb = half ? br2 : br1;

    __shared__ short Als[128 * 72];   // A[m][k], row stride 72 (2-way-free banks)
    __shared__ short Bls[192 * 64];   // B[(seg*64+n)][k], XOR-swizzled within row

    const int tid = threadIdx.x;
    const int l   = tid & 63;
    const int w   = tid >> 6;
    const int wm  = w >> 1, wn = w & 1;
    const int lr  = l & 15;
    const int lk  = (l >> 4) * 8;

    f32x4 acc[3][4][2];
#pragma unroll
    for (int s = 0; s < 3; ++s)
#pragma unroll
        for (int mi = 0; mi < 4; ++mi)
#pragma unroll
            for (int ni = 0; ni < 2; ++ni) acc[s][mi][ni] = (f32x4){0.f,0.f,0.f,0.f};

    const int arowL = tid >> 4;       // 0..15 row within pass
    const int kq    = tid & 15;       // float4 index within 64-k slice

    for (int ks = 0; ks < 4; ++ks) {
        // ---- stage A: 128 rows x 64 k, fp32->bf16, fully coalesced ----
#pragma unroll
        for (int ps = 0; ps < 8; ++ps) {
            const int rl = ps * 16 + arowL;
            int g = chunkid * CHUNK + rl;
            if (g > MROWS - 1) g = MROWS - 1;     // pad rows clamp (in-bounds garbage)
            const float4 v = *reinterpret_cast<const float4*>(
                x + (size_t)g * DDIM + half * HH + ks * 64 + kq * 4);
            short4 p;
            p.x = f2bf(v.x); p.y = f2bf(v.y); p.z = f2bf(v.z); p.w = f2bf(v.w);
            *reinterpret_cast<short4*>(&Als[rl * 72 + kq * 4]) = p;
        }
        // ---- stage B: 3 segs x 64 n x 64 k from Wt, b128 copy + XOR swizzle ----
#pragma unroll
        for (int i = 0; i < 6; ++i) {
            const int gidx = tid + i * 256;       // 0..1535
            const int row  = gidx >> 3;           // seg*64+n  (0..191)
            const int j8   = gidx & 7;
            const int seg  = row >> 6;
            const int n    = row & 63;
            const bf16x8 v = *reinterpret_cast<const bf16x8*>(
                Wt + ((size_t)half * N3 + seg * 256 + nt * 64 + n) * 256 + ks * 64 + j8 * 8);
            const int dst = row * 64 + ((j8 * 8) ^ ((n & 7) << 3));
            *reinterpret_cast<bf16x8*>(&Bls[dst]) = v;
        }
        __syncthreads();

#pragma unroll
        for (int kk = 0; kk < 2; ++kk) {
            bf16x8 af[4];
#pragma unroll
            for (int mi = 0; mi < 4; ++mi)
                af[mi] = *reinterpret_cast<const bf16x8*>(
                    &Als[(wm * 64 + mi * 16 + lr) * 72 + kk * 32 + lk]);
#pragma unroll
            for (int seg = 0; seg < 3; ++seg)
#pragma unroll
                for (int ni = 0; ni < 2; ++ni) {
                    const int n = wn * 32 + ni * 16 + lr;
                    const bf16x8 bv = *reinterpret_cast<const bf16x8*>(
                        &Bls[(seg * 64 + n) * 64 + ((kk * 32 + lk) ^ ((n & 7) << 3))]);
#pragma unroll
                    for (int mi = 0; mi < 4; ++mi)
                        acc[seg][mi][ni] = __builtin_amdgcn_mfma_f32_16x16x32_bf16(
                            af[mi], bv, acc[seg][mi][ni], 0, 0, 0);
                }
        }
        __syncthreads();
    }

    // ---- epilogue: pack (f,u) -> fu, r -> out. C/D: col=lane&15, row=(l>>4)*4+q ----
#pragma unroll
    for (int mi = 0; mi < 4; ++mi) {
        const int rl0 = wm * 64 + mi * 16 + (l >> 4) * 4;
#pragma unroll
        for (int ni = 0; ni < 2; ++ni) {
            const int col = nt * 64 + wn * 32 + ni * 16 + lr;   // 0..255
            const float bfv = bfb[col];
            const float brv = brb[col];
            const f32x4 aX = acc[0][mi][ni];
            const f32x4 aF = acc[1][mi][ni];
            const f32x4 aR = acc[2][mi][ni];
#pragma unroll
            for (int q = 0; q < 4; ++q) {
                const int rl = rl0 + q;
                if (rl < CHUNK) {
                    const size_t row = (size_t)chunkid * CHUNK + rl;
                    const size_t idx = row * DDIM + half * HH + col;
                    const float xt = aX[q];
                    const float f  = sigmoidf_(aF[q] + bfv);
                    const float r  = sigmoidf_(aR[q] + brv);
                    const float u  = xt - f * xt;
                    const uint32_t pk = ((uint32_t)(uint16_t)f2bf(u) << 16)
                                      | (uint16_t)f2bf(f);
                    fu[idx]  = pk;
                    out[idx] = r;
                }
            }
        }
    }
}

// ---------------- scan_pass1: per-(col, chunk) (P, S) ----------------
// grid (256, 4) x 256 thr. wave = 64 consecutive cols, one chunk.
__global__ __launch_bounds__(256) void scan_pass1(
    const uint32_t* __restrict__ fu, float2* __restrict__ pstab)
{
    const int col = blockIdx.x * 64 + (threadIdx.x & 63);   // 0..16383
    const int ch  = blockIdx.y * 4 + (threadIdx.x >> 6);    // 0..15
    if (ch >= 15) return;                                    // last chunk unneeded
    const int b = col >> 9, c = col & 511;
    size_t idx = ((size_t)b * TLEN + ch * CHUNK) * DDIM + c;

    float P = 1.f, S = 0.f;
#pragma unroll 5
    for (int t = 0; t < CHUNK; ++t, idx += DDIM) {
        const uint32_t wv = fu[idx];
        const float f = __uint_as_float(wv << 16);
        const float u = __uint_as_float(wv & 0xffff0000u);
        S = __builtin_fmaf(f, S, u);
        P *= f;
    }
    pstab[ch * 16384 + col] = make_float2(P, S);
}

// ---------------- scan_combine: 16-step prefix per col -> c0 table ----------------
__global__ __launch_bounds__(256) void scan_combine(
    const float2* __restrict__ pstab, float* __restrict__ c0tab)
{
    const int col = blockIdx.x * 256 + threadIdx.x;   // 0..16383
    float c = 0.f;
#pragma unroll
    for (int ch = 0; ch < 16; ++ch) {
        c0tab[ch * 16384 + col] = c;
        if (ch < 15) {
            const float2 ps = pstab[ch * 16384 + col];
            c = __builtin_fmaf(ps.x, c, ps.y);
        }
    }
}

// ---------------- scan_pass2: exact scan from c0 + highway ----------------
// grid (128, 4) x 256 thr. thread = 2 adjacent cols x one chunk.
__global__ __launch_bounds__(256) void scan_pass2(
    const float* __restrict__ x, const uint32_t* __restrict__ fu,
    const float* __restrict__ c0tab, float* __restrict__ out)
{
    const int cp = blockIdx.x * 64 + (threadIdx.x & 63);    // col pair 0..8191
    const int ch = blockIdx.y * 4 + (threadIdx.x >> 6);     // 0..15
    const int b  = cp >> 8;
    const int c  = (cp & 255) * 2;
    const int gcol = b * DDIM + c;
    size_t idx = ((size_t)b * TLEN + ch * CHUNK) * DDIM + c;

    float c0 = c0tab[ch * 16384 + gcol];
    float c1 = c0tab[ch * 16384 + gcol + 1];
#pragma unroll 5
    for (int t = 0; t < CHUNK; ++t, idx += DDIM) {
        const uint2  wv = *reinterpret_cast<const uint2*>(fu + idx);
        const float2 rv = *reinterpret_cast<const float2*>(out + idx);
        const float2 xv = *reinterpret_cast<const float2*>(x + idx);
        const float f0 = __uint_as_float(wv.x << 16);
        const float u0 = __uint_as_float(wv.x & 0xffff0000u);
        const float f1 = __uint_as_float(wv.y << 16);
        const float u1 = __uint_as_float(wv.y & 0xffff0000u);
        c0 = __builtin_fmaf(f0, c0, u0);
        c1 = __builtin_fmaf(f1, c1, u1);
        float2 h;
        h.x = __builtin_fmaf(rv.x, c0 - xv.x, xv.x);
        h.y = __builtin_fmaf(rv.y, c1 - xv.y, xv.y);
        *reinterpret_cast<float2*>(out + idx) = h;
    }
}

// ================= round-3 fallback kernels (proven; ws < WS_NEED) =================
__global__ __launch_bounds__(256) void gemm_gates_v3(
    const float* __restrict__ x,
    const float* __restrict__ W1, const float* __restrict__ bf1, const float* __restrict__ br1,
    const float* __restrict__ W2, const float* __restrict__ bf2, const float* __restrict__ br2,
    __hip_bfloat16* __restrict__ xt_ws, __hip_bfloat16* __restrict__ f_ws,
    float* __restrict__ out)
{
    const int half = blockIdx.z;
    const float* __restrict__ W   = half ? W2  : W1;
    const float* __restrict__ bfb = half ? bf2 : bf1;
    const float* __restrict__ brb = half ? br2 : br1;
    const int id  = blockIdx.x;
    const int swz = (id & 7) * 375 + (id >> 3);
    const int n0  = (swz % 6) * 128;
    const int m0  = (swz / 6) * 128;
    __shared__ short Als[128 * 40];
    __shared__ short Bls[128 * 40];
    const int tid = threadIdx.x;
    const int l   = tid & 63;
    const int w   = tid >> 6;
    const int wm  = w >> 1, wn = w & 1;
    const int lr  = l & 15;
    const int lk  = (l >> 4) * 8;
    f32x4 acc[4][4];
#pragma unroll
    for (int mi = 0; mi < 4; ++mi)
#pragma unroll
        for (int ni = 0; ni < 4; ++ni) acc[mi][ni] = (f32x4){0.f, 0.f, 0.f, 0.f};
    const int arow = tid >> 1;
    const int akh  = (tid & 1) * 16;
    const float* aptr = x + (size_t)(m0 + arow) * DDIM + half * HH + akh;
    const int bk   = tid >> 3;
    const int bng0 = tid & 7;
    for (int k0 = 0; k0 < HH; k0 += 32) {
        {
            const float4 v0 = *reinterpret_cast<const float4*>(aptr + k0 + 0);
            const float4 v1 = *reinterpret_cast<const float4*>(aptr + k0 + 4);
            const float4 v2 = *reinterpret_cast<const float4*>(aptr + k0 + 8);
            const float4 v3 = *reinterpret_cast<const float4*>(aptr + k0 + 12);
            bf16x8 p0, p1;
            p0[0]=f2bf(v0.x); p0[1]=f2bf(v0.y); p0[2]=f2bf(v0.z); p0[3]=f2bf(v0.w);
            p0[4]=f2bf(v1.x); p0[5]=f2bf(v1.y); p0[6]=f2bf(v1.z); p0[7]=f2bf(v1.w);
            p1[0]=f2bf(v2.x); p1[1]=f2bf(v2.y); p1[2]=f2bf(v2.z); p1[3]=f2bf(v2.w);
            p1[4]=f2bf(v3.x); p1[5]=f2bf(v3.y); p1[6]=f2bf(v3.z); p1[7]=f2bf(v3.w);
            short* dst = &Als[arow * 40 + akh];
            *reinterpret_cast<bf16x8*>(dst)     = p0;
            *reinterpret_cast<bf16x8*>(dst + 8) = p1;
        }
#pragma unroll
        for (int i = 0; i < 4; ++i) {
            const int ng = bng0 + 8 * i;
            const float4 v = *reinterpret_cast<const float4*>(
                W + (size_t)(k0 + bk) * N3 + n0 + ng * 4);
            Bls[(ng * 4 + 0) * 40 + bk] = f2bf(v.x);
            Bls[(ng * 4 + 1) * 40 + bk] = f2bf(v.y);
            Bls[(ng * 4 + 2) * 40 + bk] = f2bf(v.z);
            Bls[(ng * 4 + 3) * 40 + bk] = f2bf(v.w);
        }
        __syncthreads();
        bf16x8 af[4], bfr[4];
#pragma unroll
        for (int mi = 0; mi < 4; ++mi)
            af[mi] = *reinterpret_cast<const bf16x8*>(
                &Als[(wm * 64 + mi * 16 + lr) * 40 + lk]);
#pragma unroll
        for (int ni = 0; ni < 4; ++ni)
            bfr[ni] = *reinterpret_cast<const bf16x8*>(
                &Bls[(wn * 64 + ni * 16 + lr) * 40 + lk]);
#pragma unroll
        for (int mi = 0; mi < 4; ++mi)
#pragma unroll
            for (int ni = 0; ni < 4; ++ni)
                acc[mi][ni] = __builtin_amdgcn_mfma_f32_16x16x32_bf16(
                    af[mi], bfr[ni], acc[mi][ni], 0, 0, 0);
        __syncthreads();
    }
    const int seg = n0 >> 8;
#pragma unroll
    for (int mi = 0; mi < 4; ++mi) {
        const int rowb = m0 + wm * 64 + mi * 16 + (l >> 4) * 4;
#pragma unroll
        for (int ni = 0; ni < 4; ++ni) {
            const int col  = wn * 64 + ni * 16 + lr;
            const int hcol = (n0 & 255) + col;
            const f32x4 a = acc[mi][ni];
            if (seg == 0) {
#pragma unroll
                for (int q = 0; q < 4; ++q) {
                    const size_t idx = (size_t)(rowb + q) * DDIM + half * HH + hcol;
                    xt_ws[idx] = __float2bfloat16(a[q]);
                }
            } else if (seg == 1) {
                const float bias = bfb[hcol];
#pragma unroll
                for (int q = 0; q < 4; ++q) {
                    const size_t idx = (size_t)(rowb + q) * DDIM + half * HH + hcol;
                    f_ws[idx] = __float2bfloat16(sigmoidf_(a[q] + bias));
                }
            } else {
                const float bias = brb[hcol];
#pragma unroll
                for (int q = 0; q < 4; ++q) {
                    const size_t idx = (size_t)(rowb + q) * DDIM + half * HH + hcol;
                    out[idx] = sigmoidf_(a[q] + bias);
                }
            }
        }
    }
}

__global__ __launch_bounds__(1024) void scan_highway_v3(
    const float* __restrict__ x,
    const __hip_bfloat16* __restrict__ xt_ws, const __hip_bfloat16* __restrict__ f_ws,
    float* __restrict__ out)
{
    __shared__ float smP[16][64];
    __shared__ float smS[16][64];
    const int tid = threadIdx.x;
    const int sl  = tid & 63;
    const int ch  = tid >> 6;
    const int s   = blockIdx.x * 64 + sl;
    const int b   = s >> 9;
    const int col = s & 511;
    const size_t base = (size_t)b * TLEN * DDIM + col;
    const size_t idx0 = base + (size_t)(ch * CHUNK) * DDIM;
    float P = 1.f, S = 0.f;
    if (ch < 15) {
        size_t idx = idx0;
#pragma unroll 5
        for (int t = 0; t < CHUNK; ++t, idx += DDIM) {
            const float f  = __bfloat162float(f_ws[idx]);
            const float xt = __bfloat162float(xt_ws[idx]);
            S = __builtin_fmaf(f, S, __builtin_fmaf(-f, xt, xt));
            P *= f;
        }
    }
    smP[ch][sl] = P;
    smS[ch][sl] = S;
    __syncthreads();
    float c = 0.f;
    for (int j = 0; j < ch; ++j)
        c = __builtin_fmaf(smP[j][sl], c, smS[j][sl]);
    size_t idx = idx0;
#pragma unroll 5
    for (int t = 0; t < CHUNK; ++t, idx += DDIM) {
        const float f  = __bfloat162float(f_ws[idx]);
        const float xt = __bfloat162float(xt_ws[idx]);
        c = __builtin_fmaf(f, c, __builtin_fmaf(-f, xt, xt));
        const float r  = out[idx];
        const float xv = x[idx];
        out[idx] = __builtin_fmaf(r, c - xv, xv);
    }
}

extern "C" void kernel_launch(void* const* d_in, const int* in_sizes, int n_in,
                              void* d_out, int out_size, void* d_ws, size_t ws_size,
                              hipStream_t stream)
{
    const float* x   = (const float*)d_in[0];
    const float* W1  = (const float*)d_in[1];
    const float* bf1 = (const float*)d_in[2];
    const float* br1 = (const float*)d_in[3];
    const float* W2  = (const float*)d_in[4];
    const float* bf2 = (const float*)d_in[5];
    const float* br2 = (const float*)d_in[6];
    float* out = (float*)d_out;
    char* ws = (char*)d_ws;

    if (ws_size >= WS_NEED) {
        uint32_t*       fu    = (uint32_t*)(ws + FU_OFF);
        __hip_bfloat16* Wt    = (__hip_bfloat16*)(ws + WT_OFF);
        float2*         pstab = (float2*)(ws + PS_OFF);
        float*          c0tab = (float*)(ws + C0_OFF);

        prep_w<<<192, 256, 0, stream>>>(W1, W2, Wt);
        gemm_scanprep<<<dim3(4, 512, 2), 256, 0, stream>>>(
            x, Wt, bf1, br1, bf2, br2, fu, out);
        scan_pass1<<<dim3(256, 4), 256, 0, stream>>>(fu, pstab);
        scan_combine<<<64, 256, 0, stream>>>(pstab, c0tab);
        scan_pass2<<<dim3(128, 4), 256, 0, stream>>>(x, fu, c0tab, out);
    } else {
        const size_t elems = (size_t)MROWS * DDIM;
        __hip_bfloat16* xt_ws = (__hip_bfloat16*)d_ws;
        __hip_bfloat16* f_ws  = xt_ws + elems;
        gemm_gates_v3<<<dim3(3000, 1, 2), 256, 0, stream>>>(
            x, W1, bf1, br1, W2, bf2, br2, xt_ws, f_ws, out);
        scan_highway_v3<<<256, 1024, 0, stream>>>(x, xt_ws, f_ws, out);
    }
}